// Round 4
// baseline (369.052 us; speedup 1.0000x reference)
//
#include <hip/hip_runtime.h>
#include <hip/hip_cooperative_groups.h>
#include <math.h>

namespace cg = cooperative_groups;

// Problem constants
#define BATCH   64
#define SAMP    32
#define SIGLEN  19530           // sum_{k=1..6} 5^k
#define NROWS   (BATCH * SAMP)  // 2048
#define NF2     (SIGLEN / 2)    // 9765 float2 per row
#define NBISECT 40              // fp32 bisection on [0,2] fixed-point after ~30 iters
#define NBLK    1024            // 4 blocks/CU on 256 CUs -> safely co-resident
#define CHUNKS_PER_B 16         // NBLK / BATCH
#define CHUNK   611             // ceil(NF2 / 16); last chunk = 600

// Level boundaries (element index): level k occupies [LB[k-1], LB[k])
// LB = {0, 5, 30, 155, 780, 3905, 19530}
__device__ __forceinline__ int level0(int l) {
    return (l >= 5) + (l >= 30) + (l >= 155) + (l >= 780) + (l >= 3905);
}

// Alignment-aware sum of squares over row[lo,hi).
// par = 2*(row&1): element e is 16B-aligned iff e % 4 == par
// (row base byte = row*78120, 78120 % 16 == 8).
__device__ __forceinline__ float sumsq_region(const float* __restrict__ row,
                                              int lo, int hi, int par, int t) {
    float acc = 0.f;
    int vstart = lo + ((par - lo) % 4 + 4) % 4;
    if (vstart > hi) vstart = hi;
    const int nvec = (hi - vstart) >> 2;
    for (int l = lo + t; l < vstart; l += 256) { float v = row[l]; acc += v * v; }
    const float4* __restrict__ p = (const float4*)(row + vstart);
    for (int j = t; j < nvec; j += 256) {
        float4 v = p[j];
        acc += v.x * v.x + v.y * v.y + v.z * v.z + v.w * v.w;
    }
    for (int l = vstart + 4 * nvec + t; l < hi; l += 256) { float v = row[l]; acc += v * v; }
    return acc;
}

// ---------------------------------------------------------------------------
// Fused cooperative kernel.
// Phase A: block bs handles rows {2bs, 2bs+1}: per-level sums -> bisection ->
//          pw[row][m] = root^(m+1)/SAMP.
// grid.sync()
// Phase B: block bs -> batch b = bs/16, chunk c = bs%16 of the output row:
//          out[b,l] = sum_s x[b,s,l] * pw[b*32+s][level(l)]
// ---------------------------------------------------------------------------
__global__ __launch_bounds__(256, 4) void fused_kernel(
        const float* __restrict__ x, float* __restrict__ pw,
        float* __restrict__ out) {
    const int t = threadIdx.x;
    __shared__ float red[4][6];
    __shared__ float w[SAMP * 6];

    // ---------------- Phase A ----------------
    #pragma unroll 1
    for (int r = 0; r < 2; ++r) {
        const int rowi = 2 * blockIdx.x + r;
        const float* __restrict__ row = x + (size_t)rowi * SIGLEN;
        const int par = (rowi & 1) * 2;

        float a1 = sumsq_region(row,    0,     5, par, t);
        float a2 = sumsq_region(row,    5,    30, par, t);
        float a3 = sumsq_region(row,   30,   155, par, t);
        float a4 = sumsq_region(row,  155,   780, par, t);
        float a5 = sumsq_region(row,  780,  3905, par, t);
        float a6 = sumsq_region(row, 3905, SIGLEN, par, t);

        #pragma unroll
        for (int off = 32; off > 0; off >>= 1) {
            a1 += __shfl_xor(a1, off);
            a2 += __shfl_xor(a2, off);
            a3 += __shfl_xor(a3, off);
            a4 += __shfl_xor(a4, off);
            a5 += __shfl_xor(a5, off);
            a6 += __shfl_xor(a6, off);
        }
        const int wave = t >> 6, lane = t & 63;
        if (lane == 0) {
            red[wave][0] = a1; red[wave][1] = a2; red[wave][2] = a3;
            red[wave][3] = a4; red[wave][4] = a5; red[wave][5] = a6;
        }
        __syncthreads();

        if (t == 0) {
            float s1 = 0.f, s2 = 0.f, s3 = 0.f, s4 = 0.f, s5 = 0.f, s6 = 0.f;
            #pragma unroll
            for (int wv = 0; wv < 4; ++wv) {
                s1 += red[wv][0]; s2 += red[wv][1]; s3 += red[wv][2];
                s4 += red[wv][3]; s5 += red[wv][4]; s6 += red[wv][5];
            }
            const float total = s1 + s2 + s3 + s4 + s5 + s6;
            const float nq = 1.0f + total;
            // phi(x), C=4, a=1: x<=4 -> x ; else 8 - 16/x
            const float phi = (nq > 4.0f) ? (8.0f - 16.0f / nq) : nq;
            const float c0 = 1.0f - phi;
            const bool fin = isfinite(c0) && isfinite(total);

            float lo = 0.0f, hi = 2.0f;
            #pragma unroll 4
            for (int i = 0; i < NBISECT; ++i) {
                const float mid = 0.5f * (lo + hi);
                const float u = mid * mid;
                const float p = ((((((s6 * u + s5) * u + s4) * u + s3) * u + s2) * u + s1) * u) + c0;
                const bool neg = p < 0.0f;   // NaN -> false -> hi = mid (matches jnp.where)
                lo = neg ? mid : lo;
                hi = neg ? hi : mid;
            }
            float root = 0.5f * (lo + hi);
            if (!fin) root = 0.0f;
            root = fminf(root, 1.0f);

            float* dst = pw + (size_t)rowi * 6;
            const float inv = 1.0f / SAMP;
            float w1 = root;
            float w2 = w1 * root, w3 = w2 * root, w4 = w3 * root, w5 = w4 * root, w6 = w5 * root;
            dst[0] = w1 * inv; dst[1] = w2 * inv; dst[2] = w3 * inv;
            dst[3] = w4 * inv; dst[4] = w5 * inv; dst[5] = w6 * inv;
        }
        __syncthreads();   // red[] reused next r
    }

    // ---------------- grid-wide barrier ----------------
    cg::this_grid().sync();

    // ---------------- Phase B ----------------
    const int b = blockIdx.x / CHUNKS_PER_B;
    const int c = blockIdx.x % CHUNKS_PER_B;
    if (t < SAMP * 6) w[t] = pw[(size_t)b * (SAMP * 6) + t];
    __syncthreads();

    const int j0 = c * CHUNK;
    int jend = j0 + CHUNK; if (jend > NF2) jend = NF2;

    const float2* __restrict__ xp = (const float2*)x + (size_t)b * (SAMP * NF2);
    float2* __restrict__ op = (float2*)out + (size_t)b * NF2;

    for (int j = j0 + t; j < jend; j += 256) {
        const int l0 = level0(2 * j);
        const int l1 = level0(2 * j + 1);
        float acc0 = 0.f, acc1 = 0.f;
        if (l0 == l1) {
            #pragma unroll 8
            for (int s = 0; s < SAMP; ++s) {
                const float ws = w[s * 6 + l0];       // broadcast LDS read
                const float2 v = xp[(size_t)s * NF2 + j];
                acc0 += v.x * ws; acc1 += v.y * ws;
            }
        } else {
            #pragma unroll 8
            for (int s = 0; s < SAMP; ++s) {
                const float2 v = xp[(size_t)s * NF2 + j];
                acc0 += v.x * w[s * 6 + l0];
                acc1 += v.y * w[s * 6 + l1];
            }
        }
        float2 r; r.x = acc0; r.y = acc1;
        op[j] = r;
    }
}

extern "C" void kernel_launch(void* const* d_in, const int* in_sizes, int n_in,
                              void* d_out, int out_size, void* d_ws, size_t ws_size,
                              hipStream_t stream) {
    const float* x = (const float*)d_in[0];   // [64,32,19530] fp32
    float* out = (float*)d_out;               // [64,19530] fp32
    float* pw = (float*)d_ws;                 // 2048*6 floats = 48 KiB scratch

    void* args[] = { (void*)&x, (void*)&pw, (void*)&out };
    hipLaunchCooperativeKernel((const void*)fused_kernel,
                               dim3(NBLK), dim3(256), args, 0, stream);
}

// Round 5
// 254.148 us; speedup vs baseline: 1.4521x; 1.4521x over previous
//
#include <hip/hip_runtime.h>
#include <math.h>

// Problem constants
#define BATCH   64
#define SAMP    32
#define SIGLEN  19530           // sum_{k=1..6} 5^k
#define NROWS   (BATCH * SAMP)  // 2048
#define NF2     (SIGLEN / 2)    // 9765 float2 per row (19530 is even)
#define NBISECT 40              // fp32 bisection on [0,2] is a fixed point after ~30
                                // iters (mid rounds to an endpoint) -> identical to 100

// Level boundaries (element index): level k occupies [LB[k-1], LB[k])
// LB = {0, 5, 30, 155, 780, 3905, 19530}

__device__ __forceinline__ int level0(int l) {
    // 0-based level index: 0..5
    return (l >= 5) + (l >= 30) + (l >= 155) + (l >= 780) + (l >= 3905);
}

// ---------------------------------------------------------------------------
// Kernel A: per-(b,s) row -> 6 per-level sums of x^2, then bisection for the
// dilatation root, then write w[m] = root^(m+1)/SAMP, m=0..5 (6 floats/row).
// One block of 256 threads per row. 160 MB total read -> HBM-bound (~25 us).
// ---------------------------------------------------------------------------
__global__ __launch_bounds__(256) void sums_bisect_kernel(
        const float* __restrict__ x, float* __restrict__ pw) {
    const int bs = blockIdx.x;               // 0..2047
    const float* __restrict__ row = x + (size_t)bs * SIGLEN;
    const int t = threadIdx.x;

    float a1 = 0.f, a2 = 0.f, a3 = 0.f, a4 = 0.f, a5 = 0.f, a6 = 0.f;

    // Levels 1..4: [0,5),[5,30),[30,155),[155,780) -- 780 elems, scalar loads
    if (t < 5)                              { float v = row[t];      a1 += v * v; }
    if (t >= 5 && t < 30)                   { float v = row[t];      a2 += v * v; }
    if (t >= 30 && t < 155)                 { float v = row[t];      a3 += v * v; }
    for (int l = 155 + t; l < 780; l += 256){ float v = row[l];      a4 += v * v; }

    // Level 5: [780,3905) = 3125 elems. float2 over [780,3904), tail 3904.
    // (row base elem index bs*19530 is even -> row+780 is 8B-aligned)
    {
        const float2* p = (const float2*)(row + 780);
        #pragma unroll 2
        for (int j = t; j < 1562; j += 256) { float2 v = p[j]; a5 += v.x * v.x + v.y * v.y; }
        if (t == 0) { float v = row[3904]; a5 += v * v; }
    }
    // Level 6: [3905,19530) = 15625 elems. Elem 3905 scalar, [3906,19530) = 7812 float2.
    {
        if (t == 64) { float v = row[3905]; a6 += v * v; }
        const float2* p = (const float2*)(row + 3906);
        #pragma unroll 4
        for (int j = t; j < 7812; j += 256) { float2 v = p[j]; a6 += v.x * v.x + v.y * v.y; }
    }

    // Wave (64-lane) butterfly reduction of the 6 accumulators
    #pragma unroll
    for (int off = 32; off > 0; off >>= 1) {
        a1 += __shfl_xor(a1, off);
        a2 += __shfl_xor(a2, off);
        a3 += __shfl_xor(a3, off);
        a4 += __shfl_xor(a4, off);
        a5 += __shfl_xor(a5, off);
        a6 += __shfl_xor(a6, off);
    }

    __shared__ float red[4][6];
    const int wave = t >> 6, lane = t & 63;
    if (lane == 0) {
        red[wave][0] = a1; red[wave][1] = a2; red[wave][2] = a3;
        red[wave][3] = a4; red[wave][4] = a5; red[wave][5] = a6;
    }
    __syncthreads();

    if (t == 0) {
        float s1 = 0.f, s2 = 0.f, s3 = 0.f, s4 = 0.f, s5 = 0.f, s6 = 0.f;
        #pragma unroll
        for (int w = 0; w < 4; ++w) {
            s1 += red[w][0]; s2 += red[w][1]; s3 += red[w][2];
            s4 += red[w][3]; s5 += red[w][4]; s6 += red[w][5];
        }
        const float total = s1 + s2 + s3 + s4 + s5 + s6;
        const float nq = 1.0f + total;
        // phi(x) with C=4, a=1: x<=4 -> x ; else 4 + 16*(1/4 - 1/x) = 8 - 16/x
        const float phi = (nq > 4.0f) ? (8.0f - 16.0f / nq) : nq;
        const float c0 = 1.0f - phi;
        const bool fin = isfinite(c0) && isfinite(total);

        float lo = 0.0f, hi = 2.0f;
        #pragma unroll 4
        for (int i = 0; i < NBISECT; ++i) {
            const float mid = 0.5f * (lo + hi);
            const float u = mid * mid;
            // poly(u) = c0 + s1 u + s2 u^2 + ... + s6 u^6  (Horner)
            const float p = ((((((s6 * u + s5) * u + s4) * u + s3) * u + s2) * u + s1) * u) + c0;
            const bool neg = p < 0.0f;      // NaN -> false -> hi = mid (matches jnp.where)
            lo = neg ? mid : lo;
            hi = neg ? hi : mid;
        }
        float root = 0.5f * (lo + hi);
        if (!fin) root = 0.0f;
        root = fminf(root, 1.0f);

        // Fold the 1/SAMP mean into the weights.
        float* dst = pw + (size_t)bs * 6;
        const float inv = 1.0f / SAMP;
        float w1 = root;
        float w2 = w1 * root, w3 = w2 * root, w4 = w3 * root, w5 = w4 * root, w6 = w5 * root;
        dst[0] = w1 * inv; dst[1] = w2 * inv; dst[2] = w3 * inv;
        dst[3] = w4 * inv; dst[4] = w5 * inv; dst[5] = w6 * inv;
    }
}

// ---------------------------------------------------------------------------
// Kernel B: out[b,l] = sum_s x[b,s,l] * pw[b,s][level(l)]   (1/32 pre-folded)
// float2 vectorized over l. Grid: (ceil(NF2/256), BATCH), block 256.
// Input re-read is mostly L3-resident (kernel A just fetched it; 160 MB < 256 MB).
// ---------------------------------------------------------------------------
__global__ __launch_bounds__(256) void scale_mean_kernel(
        const float* __restrict__ x, const float* __restrict__ pw,
        float* __restrict__ out) {
    const int b = blockIdx.y;
    const int t = threadIdx.x;

    __shared__ float w[SAMP * 6];   // [s*6 + lev]
    if (t < SAMP * 6) w[t] = pw[(size_t)b * (SAMP * 6) + t];
    __syncthreads();

    const int j = blockIdx.x * 256 + t;      // float2 index within row
    if (j >= NF2) return;

    const int l0 = 2 * j;
    const int levA = level0(l0);
    const int levB = level0(l0 + 1);

    const float2* __restrict__ x2p = (const float2*)x;
    const unsigned base = (unsigned)b * (SAMP * NF2) + (unsigned)j;

    float acc0 = 0.f, acc1 = 0.f;
    if (levA == levB) {
        #pragma unroll
        for (int s = 0; s < SAMP; ++s) {
            const float  ws = w[s * 6 + levA];     // single broadcast LDS read
            const float2 v  = x2p[base + (unsigned)s * NF2];
            acc0 += v.x * ws;
            acc1 += v.y * ws;
        }
    } else {                                       // 3 straddling threads per row
        #pragma unroll
        for (int s = 0; s < SAMP; ++s) {
            const float2 v = x2p[base + (unsigned)s * NF2];
            acc0 += v.x * w[s * 6 + levA];
            acc1 += v.y * w[s * 6 + levB];
        }
    }

    float2 r; r.x = acc0; r.y = acc1;
    ((float2*)out)[(unsigned)b * NF2 + (unsigned)j] = r;
}

extern "C" void kernel_launch(void* const* d_in, const int* in_sizes, int n_in,
                              void* d_out, int out_size, void* d_ws, size_t ws_size,
                              hipStream_t stream) {
    const float* x = (const float*)d_in[0];   // [64,32,19530] fp32
    float* out = (float*)d_out;               // [64,19530] fp32
    float* pw = (float*)d_ws;                 // 2048*6 floats = 48 KiB scratch

    // Kernel A: one block per (b,s) row
    sums_bisect_kernel<<<NROWS, 256, 0, stream>>>(x, pw);

    // Kernel B: scale + mean over samples
    dim3 gridB((NF2 + 255) / 256, BATCH);
    scale_mean_kernel<<<gridB, 256, 0, stream>>>(x, pw, out);
}